// Round 9
// baseline (238.913 us; speedup 1.0000x reference)
//
#include <hip/hip_runtime.h>

#define STEPV (1.0f / 7.0f)
#define L_COORD 5.0f
#define L_NOOBJ 0.5f
#define EPSV 1e-6f

#define TILE 128                               // cells per block
#define FLOATS_PER_CELL 30
#define TILE_F4 (TILE * FLOATS_PER_CELL / 4)   // 960 float4 per tensor
#define NTHREADS 384
#define NTILES 6272                            // 802816 / 128
#define NGROUPS 49                             // 6272 = 49 * 128
#define GROUP_SZ 128

typedef const __attribute__((address_space(1))) void cg_void;
typedef __attribute__((address_space(3))) void ls_void;

__global__ __launch_bounds__(NTHREADS) void yolo_loss_kernel(
    const float* __restrict__ pred,
    const float* __restrict__ tgt,
    float* __restrict__ partials,
    unsigned* __restrict__ cnt,      // [NGROUPS] group counters + [1] master
    float* __restrict__ out,
    float invN)
{
    __shared__ float4 bufP4[TILE_F4];
    __shared__ float4 bufT4[TILE_F4];

    const int tid  = threadIdx.x;
    const int w    = tid >> 6;        // wave 0..5
    const int lane = tid & 63;
    const int bid  = blockIdx.x;

    // ---- async staging: direct global -> LDS (wave-uniform LDS base, per-lane global)
    if (w < 3) {
        const float4* g = reinterpret_cast<const float4*>(pred)
                        + (size_t)bid * TILE_F4 + w * 320 + lane;
        #pragma unroll
        for (int i = 0; i < 5; ++i)
            __builtin_amdgcn_global_load_lds((cg_void*)(g + i * 64),
                                             (ls_void*)(bufP4 + w * 320 + i * 64),
                                             16, 0, 0);
    } else {
        const float4* g = reinterpret_cast<const float4*>(tgt)
                        + (size_t)bid * TILE_F4 + (w - 3) * 320 + lane;
        #pragma unroll
        for (int i = 0; i < 5; ++i)
            __builtin_amdgcn_global_load_lds((cg_void*)(g + i * 64),
                                             (ls_void*)(bufT4 + (w - 3) * 320 + i * 64),
                                             16, 0, 0);
    }
    __syncthreads();   // drains vmcnt before barrier

    const float* bufP = reinterpret_cast<const float*>(bufP4);
    const float* bufT = reinterpret_cast<const float*>(bufT4);

    float loss = 0.0f;

    if (tid < TILE) {
        // ---- waves 0-1: box/conf losses on channels 0..9, one thread per cell
        const int cid  = tid;
        const int cell = bid * TILE + cid;
        const float* p = bufP + cid * FLOATS_PER_CELL;
        const float* t = bufT + cid * FLOATS_PER_CELL;
        float pv[10], tv[10];
        #pragma unroll
        for (int k = 0; k < 5; ++k) {
            float2 a = *reinterpret_cast<const float2*>(p + 2 * k);
            pv[2 * k] = a.x; pv[2 * k + 1] = a.y;
            float2 b = *reinterpret_cast<const float2*>(t + 2 * k);
            tv[2 * k] = b.x; tv[2 * k + 1] = b.y;
        }

        int ij = cell % 49;
        float gy = (float)(ij / 7);
        float gx = (float)(ij % 7);

        float iou[2];
        #pragma unroll
        for (int b = 0; b < 2; ++b) {
            const float* pb = pv + b * 5;
            const float* tb = tv + b * 5;
            float x1 = fminf(fmaxf((pb[0] + gx) * STEPV - pb[2] * 0.5f, 0.f), 1.f);
            float y1 = fminf(fmaxf((pb[1] + gy) * STEPV - pb[3] * 0.5f, 0.f), 1.f);
            float w1 = fminf(fmaxf(pb[2], 0.f), 1.f);
            float h1 = fminf(fmaxf(pb[3], 0.f), 1.f);
            float x2 = fminf(fmaxf((tb[0] + gx) * STEPV - tb[2] * 0.5f, 0.f), 1.f);
            float y2 = fminf(fmaxf((tb[1] + gy) * STEPV - tb[3] * 0.5f, 0.f), 1.f);
            float w2 = fminf(fmaxf(tb[2], 0.f), 1.f);
            float h2 = fminf(fmaxf(tb[3], 0.f), 1.f);
            float iw = fmaxf(w1 + w2 - (fmaxf(x1 + w1, x2 + w2) - fminf(x1, x2)), 0.f);
            float ih = fmaxf(h1 + h2 - (fmaxf(y1 + h1, y2 + h2) - fminf(y1, y2)), 0.f);
            float inter = iw * ih;
            float uni = w1 * h1 + w2 * h2 - inter + EPSV;
            iou[b] = inter / uni;
        }
        int best = (iou[1] > iou[0]) ? 1 : 0;   // argmax tie -> index 0

        float obj_l = 0.f, noobj_l = 0.f, xy_l = 0.f, wh_l = 0.f;
        #pragma unroll
        for (int b = 0; b < 2; ++b) {
            const float* pb = pv + b * 5;
            const float* tb = tv + b * 5;
            bool obj = (tb[4] > 0.f) && (b == best);
            float dc = pb[4] - tb[4];
            dc *= dc;
            if (obj) {
                obj_l += dc;
                float dx = pb[0] - tb[0];
                float dy = pb[1] - tb[1];
                xy_l += dx * dx + dy * dy;
                float sw = sqrtf(tb[2] + EPSV) - sqrtf(fmaxf(pb[2], 0.f) + EPSV);
                float sh = sqrtf(tb[3] + EPSV) - sqrtf(fmaxf(pb[3], 0.f) + EPSV);
                wh_l += sw * sw + sh * sh;
            } else {
                noobj_l += dc;
            }
        }
        loss = obj_l + L_NOOBJ * noobj_l + L_COORD * (xy_l + wh_l);
    } else {
        // ---- waves 2-5: class loss, two threads per cell (10 channels each)
        const int q   = tid - TILE;
        const int cid = q >> 1;
        const int sub = q & 1;
        const float* p = bufP + cid * FLOATS_PER_CELL + 10 + sub * 10;
        const float* t = bufT + cid * FLOATS_PER_CELL + 10 + sub * 10;
        float t4 = bufT[cid * FLOATS_PER_CELL + 4];
        float t9 = bufT[cid * FLOATS_PER_CELL + 9];
        bool sig = (t4 > 0.f) || (t9 > 0.f);

        float cls = 0.f;
        #pragma unroll
        for (int k = 0; k < 5; ++k) {
            float2 a = *reinterpret_cast<const float2*>(p + 2 * k);
            float2 b = *reinterpret_cast<const float2*>(t + 2 * k);
            float d0 = a.x - b.x;
            float d1 = a.y - b.y;
            cls += d0 * d0 + d1 * d1;
        }
        loss = sig ? cls : 0.0f;
    }

    // ---- wave shuffle reduce -> LDS -> one plain store per block
    #pragma unroll
    for (int off = 32; off > 0; off >>= 1)
        loss += __shfl_down(loss, off, 64);

    __shared__ float wsum[6];
    __shared__ int sh_last;
    if (lane == 0) wsum[w] = loss;
    __syncthreads();
    if (tid == 0) {
        float s = 0.f;
        #pragma unroll
        for (int k = 0; k < 6; ++k) s += wsum[k];
        partials[bid] = s;
        __threadfence();                       // release partial before counting
        int last = 0;
        unsigned old = atomicAdd(&cnt[bid >> 7], 1u);   // group counter (49 addrs)
        if (old == GROUP_SZ - 1) {
            unsigned old2 = atomicAdd(&cnt[NGROUPS], 1u);  // master
            last = (old2 == NGROUPS - 1);
        }
        sh_last = last;
    }
    __syncthreads();

    // ---- last block to finish folds the final reduction (fixed-order, deterministic)
    if (sh_last) {
        __threadfence();                       // acquire: see all partials
        double s = 0.0;
        for (int i = tid; i < NTILES; i += NTHREADS)
            s += (double)partials[i];

        #pragma unroll
        for (int off = 32; off > 0; off >>= 1)
            s += __shfl_down(s, off, 64);

        __shared__ double dsum[6];
        if (lane == 0) dsum[w] = s;
        __syncthreads();
        if (tid == 0) {
            double tot = 0.0;
            #pragma unroll
            for (int k = 0; k < 6; ++k) tot += dsum[k];
            out[0] = (float)(tot * (double)invN);
        }
    }
}

extern "C" void kernel_launch(void* const* d_in, const int* in_sizes, int n_in,
                              void* d_out, int out_size, void* d_ws, size_t ws_size,
                              hipStream_t stream)
{
    const float* pred = (const float*)d_in[0];
    const float* tgt  = (const float*)d_in[1];
    float* out = (float*)d_out;

    // d_ws layout: partials[NTILES] floats | cnt[NGROUPS+1] uints
    float*    partials = (float*)d_ws;
    unsigned* cnt      = (unsigned*)((char*)d_ws + NTILES * sizeof(float));

    int ncells = in_sizes[0] / FLOATS_PER_CELL;   // 802816
    int N = ncells / 49;

    // zero the done-counters each call (graph-safe async memset, 200 B)
    hipMemsetAsync(cnt, 0, (NGROUPS + 1) * sizeof(unsigned), stream);

    yolo_loss_kernel<<<NTILES, NTHREADS, 0, stream>>>(
        pred, tgt, partials, cnt, out, 1.0f / (float)N);
}

// Round 10
// 36.181 us; speedup vs baseline: 6.6033x; 6.6033x over previous
//
#include <hip/hip_runtime.h>

#define STEPV (1.0f / 7.0f)
#define L_COORD 5.0f
#define L_NOOBJ 0.5f
#define EPSV 1e-6f

#define TILE 128                               // cells per block
#define FLOATS_PER_CELL 30
#define TILE_F4 (TILE * FLOATS_PER_CELL / 4)   // 960 float4 per tensor
// block: 384 threads = 6 waves; waves 0-2 stage pred, waves 3-5 stage tgt
// each wave stages 320 f4 = 5 x global_load_lds_dwordx4
// LDS 30720 B -> 5 blocks/CU x 6 waves = 30/32 waves per CU (occupancy sweet spot)

typedef const __attribute__((address_space(1))) void cg_void;
typedef __attribute__((address_space(3))) void ls_void;

__global__ __launch_bounds__(384) void yolo_loss_kernel(
    const float* __restrict__ pred,
    const float* __restrict__ tgt,
    float* __restrict__ partials)
{
    __shared__ float4 bufP4[TILE_F4];
    __shared__ float4 bufT4[TILE_F4];

    const int tid  = threadIdx.x;
    const int w    = tid >> 6;        // wave 0..5
    const int lane = tid & 63;

    // ---- async staging: direct global -> LDS, no VGPR round-trip, no ds_write
    if (w < 3) {
        const float4* g = reinterpret_cast<const float4*>(pred)
                        + (size_t)blockIdx.x * TILE_F4 + w * 320 + lane;
        #pragma unroll
        for (int i = 0; i < 5; ++i)
            __builtin_amdgcn_global_load_lds((cg_void*)(g + i * 64),
                                             (ls_void*)(bufP4 + w * 320 + i * 64),
                                             16, 0, 0);
    } else {
        const float4* g = reinterpret_cast<const float4*>(tgt)
                        + (size_t)blockIdx.x * TILE_F4 + (w - 3) * 320 + lane;
        #pragma unroll
        for (int i = 0; i < 5; ++i)
            __builtin_amdgcn_global_load_lds((cg_void*)(g + i * 64),
                                             (ls_void*)(bufT4 + (w - 3) * 320 + i * 64),
                                             16, 0, 0);
    }
    __syncthreads();   // compiler drains vmcnt before s_barrier

    const float* bufP = reinterpret_cast<const float*>(bufP4);
    const float* bufT = reinterpret_cast<const float*>(bufT4);

    float loss = 0.0f;

    if (tid < TILE) {
        // ---- waves 0-1: box/conf losses on channels 0..9, one thread per cell
        const int cid  = tid;
        const int cell = blockIdx.x * TILE + cid;
        const float* p = bufP + cid * FLOATS_PER_CELL;
        const float* t = bufT + cid * FLOATS_PER_CELL;
        float pv[10], tv[10];
        #pragma unroll
        for (int k = 0; k < 5; ++k) {
            float2 a = *reinterpret_cast<const float2*>(p + 2 * k);
            pv[2 * k] = a.x; pv[2 * k + 1] = a.y;
            float2 b = *reinterpret_cast<const float2*>(t + 2 * k);
            tv[2 * k] = b.x; tv[2 * k + 1] = b.y;
        }

        int ij = cell % 49;
        float gy = (float)(ij / 7);
        float gx = (float)(ij % 7);

        float iou[2];
        #pragma unroll
        for (int b = 0; b < 2; ++b) {
            const float* pb = pv + b * 5;
            const float* tb = tv + b * 5;
            float x1 = fminf(fmaxf((pb[0] + gx) * STEPV - pb[2] * 0.5f, 0.f), 1.f);
            float y1 = fminf(fmaxf((pb[1] + gy) * STEPV - pb[3] * 0.5f, 0.f), 1.f);
            float w1 = fminf(fmaxf(pb[2], 0.f), 1.f);
            float h1 = fminf(fmaxf(pb[3], 0.f), 1.f);
            float x2 = fminf(fmaxf((tb[0] + gx) * STEPV - tb[2] * 0.5f, 0.f), 1.f);
            float y2 = fminf(fmaxf((tb[1] + gy) * STEPV - tb[3] * 0.5f, 0.f), 1.f);
            float w2 = fminf(fmaxf(tb[2], 0.f), 1.f);
            float h2 = fminf(fmaxf(tb[3], 0.f), 1.f);
            float iw = fmaxf(w1 + w2 - (fmaxf(x1 + w1, x2 + w2) - fminf(x1, x2)), 0.f);
            float ih = fmaxf(h1 + h2 - (fmaxf(y1 + h1, y2 + h2) - fminf(y1, y2)), 0.f);
            float inter = iw * ih;
            float uni = w1 * h1 + w2 * h2 - inter + EPSV;
            iou[b] = inter / uni;
        }
        int best = (iou[1] > iou[0]) ? 1 : 0;   // argmax tie -> index 0

        float obj_l = 0.f, noobj_l = 0.f, xy_l = 0.f, wh_l = 0.f;
        #pragma unroll
        for (int b = 0; b < 2; ++b) {
            const float* pb = pv + b * 5;
            const float* tb = tv + b * 5;
            bool obj = (tb[4] > 0.f) && (b == best);
            float dc = pb[4] - tb[4];
            dc *= dc;
            if (obj) {
                obj_l += dc;
                float dx = pb[0] - tb[0];
                float dy = pb[1] - tb[1];
                xy_l += dx * dx + dy * dy;
                float sw = sqrtf(tb[2] + EPSV) - sqrtf(fmaxf(pb[2], 0.f) + EPSV);
                float sh = sqrtf(tb[3] + EPSV) - sqrtf(fmaxf(pb[3], 0.f) + EPSV);
                wh_l += sw * sw + sh * sh;
            } else {
                noobj_l += dc;
            }
        }
        loss = obj_l + L_NOOBJ * noobj_l + L_COORD * (xy_l + wh_l);
    } else {
        // ---- waves 2-5: class loss, two threads per cell (10 channels each)
        const int q   = tid - TILE;         // 0..255
        const int cid = q >> 1;             // cell in tile
        const int sub = q & 1;              // 0: ch 10-19, 1: ch 20-29
        const float* p = bufP + cid * FLOATS_PER_CELL + 10 + sub * 10;
        const float* t = bufT + cid * FLOATS_PER_CELL + 10 + sub * 10;
        float t4 = bufT[cid * FLOATS_PER_CELL + 4];
        float t9 = bufT[cid * FLOATS_PER_CELL + 9];
        bool sig = (t4 > 0.f) || (t9 > 0.f);

        float cls = 0.f;
        #pragma unroll
        for (int k = 0; k < 5; ++k) {
            float2 a = *reinterpret_cast<const float2*>(p + 2 * k);
            float2 b = *reinterpret_cast<const float2*>(t + 2 * k);
            float d0 = a.x - b.x;
            float d1 = a.y - b.y;
            cls += d0 * d0 + d1 * d1;
        }
        loss = sig ? cls : 0.0f;
    }

    // ---- wave shuffle reduce -> LDS -> one plain store per block (NO atomic,
    // NO device fence: cross-XCD visibility comes from the kernel boundary)
    #pragma unroll
    for (int off = 32; off > 0; off >>= 1)
        loss += __shfl_down(loss, off, 64);

    __shared__ float wsum[6];
    if (lane == 0) wsum[w] = loss;
    __syncthreads();
    if (tid == 0) {
        float s = 0.f;
        #pragma unroll
        for (int k = 0; k < 6; ++k) s += wsum[k];
        partials[blockIdx.x] = s;
    }
}

__global__ __launch_bounds__(1024) void yolo_finalize(
    const float* __restrict__ partials,
    float* __restrict__ out, int nparts, float invN)
{
    double s = 0.0;
    for (int i = threadIdx.x; i < nparts; i += 1024)
        s += (double)partials[i];

    #pragma unroll
    for (int off = 32; off > 0; off >>= 1)
        s += __shfl_down(s, off, 64);

    __shared__ double wsum[16];
    int lane = threadIdx.x & 63;
    int wid  = threadIdx.x >> 6;
    if (lane == 0) wsum[wid] = s;
    __syncthreads();
    if (threadIdx.x == 0) {
        double tot = 0.0;
        #pragma unroll
        for (int k = 0; k < 16; ++k) tot += wsum[k];
        out[0] = (float)(tot * (double)invN);
    }
}

extern "C" void kernel_launch(void* const* d_in, const int* in_sizes, int n_in,
                              void* d_out, int out_size, void* d_ws, size_t ws_size,
                              hipStream_t stream)
{
    const float* pred = (const float*)d_in[0];
    const float* tgt  = (const float*)d_in[1];
    float* out      = (float*)d_out;
    float* partials = (float*)d_ws;    // one float per block, all written each call

    int ncells = in_sizes[0] / FLOATS_PER_CELL;   // 802816
    int N = ncells / 49;
    int blocks = ncells / TILE;                   // 6272, exact

    yolo_loss_kernel<<<blocks, 384, 0, stream>>>(pred, tgt, partials);
    yolo_finalize<<<1, 1024, 0, stream>>>(partials, out, blocks, 1.0f / (float)N);
}